// Round 15
// baseline (134.751 us; speedup 1.0000x reference)
//
#include <hip/hip_runtime.h>
#include <stdint.h>

// Problem constants (fixed by setup_inputs: B=16, A=9, H=W=192)
#define A_NUM    9
#define W_FEAT   192
#define H_FEAT   192
#define K_FEAT   (W_FEAT * H_FEAT)     // 36864 positions
#define N_ANCH   (K_FEAT * A_NUM)      // 331776 anchors per batch
#define BATCH    16
#define PRE_NMS  6000
#define POST_NMS 300
#define CAP      8192                  // fallback candidate buffer
#define CHUNK    4096                  // elements per compact chunk
#define BPB      (N_ANCH / CHUNK)      // 81 chunks per batch
#define CPA      (K_FEAT / CHUNK)      // 9 chunks per anchor-plane
#define SORT2    2048                  // fast-path sort size
#define NWORD    (SORT2 / 64)          // 32 mask words per row
#define SLOTS    64                    // per-chunk cand slots (mean 16, 12 sigma)

// Static fast-path threshold: key16 >= 0xBF7F <=> score >= 0.99609375 (p = 1/256
// exactly for Uniform[0,1)). E[cnt]=1296/batch, sigma=36 — matches the dynamic
// threshold bin of all passing rounds R3-R14. Any distribution shift is caught
// dynamically (slot overflow / <300 keeps) -> in-block exact fallback.
#define T2KEY    0xBF7Fu

typedef unsigned long long u64;

// py-faster-rcnn standard anchors (base 16, ratios .5/1/2, scales 8/16/32)
__constant__ float c_anchors[A_NUM][4] = {
    { -84.f,  -40.f,  99.f,  55.f},
    {-176.f,  -88.f, 191.f, 103.f},
    {-360.f, -184.f, 375.f, 199.f},
    { -56.f,  -56.f,  71.f,  71.f},
    {-120.f, -120.f, 135.f, 135.f},
    {-248.f, -248.f, 263.f, 263.f},
    { -36.f,  -80.f,  51.f,  95.f},
    { -80.f, -168.f,  95.f, 183.f},
    {-168.f, -344.f, 183.f, 359.f},
};

__device__ __forceinline__ unsigned key_bits(float s) {
    unsigned ub = __float_as_uint(s);
    return (ub & 0x80000000u) ? ~ub : (ub | 0x80000000u);
}

__device__ __forceinline__ const float* chunk_ptr(const float* scores, int blk,
                                                  int& b, int& a, int& koff) {
    b = blk / BPB;
    int chunk = blk - b * BPB;
    a = chunk / CPA;
    koff = (chunk - a * CPA) * CHUNK;
    return scores + ((size_t)(b * 2 * A_NUM + A_NUM + a)) * K_FEAT + koff;
}

// ballot-aggregated LDS histogram add: one atomic per distinct bin per wave
__device__ __forceinline__ void hist_add(unsigned* lh, unsigned bin) {
    unsigned long long peers = __ballot(1);
    #pragma unroll
    for (int bit = 0; bit < 8; ++bit) {
        unsigned long long vote = __ballot((bin >> bit) & 1);
        peers &= ((bin >> bit) & 1) ? vote : ~vote;
    }
    int lane = threadIdx.x & 63;
    if (lane == (int)(__ffsll((long long)peers) - 1))
        atomicAdd(&lh[bin], (unsigned)__popcll(peers));
}

__device__ __forceinline__ float4 decode_box(unsigned n, const float* __restrict__ deltas,
                                             int b, float wmax, float hmax) {
    unsigned kk = n / A_NUM, a = n - kk * A_NUM;
    unsigned hh = kk / W_FEAT, ww = kk - hh * W_FEAT;
    size_t dbase = ((size_t)(b * 4 * A_NUM + 4 * a)) * K_FEAT + kk;
    float dx = deltas[dbase];
    float dy = deltas[dbase + (size_t)K_FEAT];
    float dw = deltas[dbase + (size_t)2 * K_FEAT];
    float dh = deltas[dbase + (size_t)3 * K_FEAT];
    float ax1 = c_anchors[a][0] + ww * 16.0f;
    float ay1 = c_anchors[a][1] + hh * 16.0f;
    float ax2 = c_anchors[a][2] + ww * 16.0f;
    float ay2 = c_anchors[a][3] + hh * 16.0f;
    float waf = ax2 - ax1 + 1.0f, haf = ay2 - ay1 + 1.0f;
    float cx = ax1 + 0.5f * waf, cy = ay1 + 0.5f * haf;
    float pcx = dx * waf + cx, pcy = dy * haf + cy;
    float pw = expf(dw) * waf, ph = expf(dh) * haf;
    float4 box;
    box.x = fminf(fmaxf(pcx - 0.5f * pw, 0.f), wmax);
    box.y = fminf(fmaxf(pcy - 0.5f * ph, 0.f), hmax);
    box.z = fminf(fmaxf(pcx + 0.5f * pw, 0.f), wmax);
    box.w = fminf(fmaxf(pcy + 0.5f * ph, 0.f), hmax);
    return box;
}

// IoU(a, c) > 0.7 — identical algebra everywhere (bit-identical decisions)
__device__ __forceinline__ bool iou_over(float4 a, float aa, float4 c, float ca) {
    float xx1 = fmaxf(a.x, c.x), yy1 = fmaxf(a.y, c.y);
    float xx2 = fminf(a.z, c.z), yy2 = fminf(a.w, c.w);
    float iw = fmaxf(xx2 - xx1 + 1.f, 0.f);
    float ih = fmaxf(yy2 - yy1 + 1.f, 0.f);
    float inter = iw * ih;
    return inter > 0.7f * (aa + ca - inter);
}

__device__ __forceinline__ u64 shflxor64(u64 v, int j) {
    unsigned lo = (unsigned)v, hi = (unsigned)(v >> 32);
    lo = __shfl_xor(lo, j, 64);
    hi = __shfl_xor(hi, j, 64);
    return ((u64)hi << 32) | lo;
}

// --- Pass 1: compact candidates >= T2KEY to fixed per-block slots ------------
// Full-overwrite (count + slots) => no init kernel, no global atomics needed.
__global__ __launch_bounds__(256) void compact_kernel(
        const float* __restrict__ scores,
        unsigned* __restrict__ cnt_blk,
        u64* __restrict__ cand) {
    __shared__ u64 sbuf[256];
    __shared__ unsigned scount;
    int tid = threadIdx.x;
    if (tid == 0) scount = 0;
    __syncthreads();
    int b, a, koff;
    const float* p = chunk_ptr(scores, blockIdx.x, b, a, koff);
    const float4* p4 = (const float4*)p;
    #pragma unroll
    for (int it = 0; it < CHUNK / 1024; ++it) {
        float4 v = p4[it * 256 + tid];
        unsigned e0 = (unsigned)(koff + (it * 256 + tid) * 4);
        float vv[4] = {v.x, v.y, v.z, v.w};
        #pragma unroll
        for (int j = 0; j < 4; ++j) {
            unsigned ub = key_bits(vv[j]);
            if ((ub >> 16) >= T2KEY) {
                unsigned n = (e0 + j) * A_NUM + a;
                unsigned pos = atomicAdd(&scount, 1u);
                if (pos < 256)
                    sbuf[pos] = ((u64)ub << 32) | (unsigned)(~n);
            }
        }
    }
    __syncthreads();
    unsigned c = scount;
    if (tid == 0) cnt_blk[blockIdx.x] = c;   // true count (overflow detected later)
    unsigned cw = c < SLOTS ? c : SLOTS;
    if (tid < cw) cand[(size_t)blockIdx.x * SLOTS + tid] = sbuf[tid];
}

// --- Pass 2: gather + hybrid register/LDS bitonic sort + decode -> bxg -------
#define KEYRD(I)  ((((u64)khi[(I)]) << 32) | klo[(I)])
#define KEYWR(I, V) do { khi[(I)] = (unsigned)((V) >> 32); klo[(I)] = (unsigned)(V); } while (0)

#define CE_SHFL(E, J, DESC) do { \
    u64 _v = shflxor64((E), (J)); \
    bool _kmax = ((DESC) == ((l & (J)) == 0)); \
    (E) = _kmax ? ((E) > _v ? (E) : _v) : ((E) < _v ? (E) : _v); \
} while (0)

#define CE_PAIR(A, B, DESC) do { \
    u64 _mx = (A) > (B) ? (A) : (B); \
    u64 _mn = (A) > (B) ? (B) : (A); \
    if (DESC) { (A) = _mx; (B) = _mn; } else { (A) = _mn; (B) = _mx; } \
} while (0)

#define LDS_PHASE(K, J) do { \
    _Pragma("unroll") \
    for (int pp = 0; pp < 2; ++pp) { \
        unsigned p = (unsigned)tid + (unsigned)pp * 512u; \
        unsigned i = ((p & ~((unsigned)(J) - 1u)) << 1) | (p & ((unsigned)(J) - 1u)); \
        unsigned ixj = i | (unsigned)(J); \
        u64 x = KEYRD(i), y = KEYRD(ixj); \
        bool dsc = ((i & (unsigned)(K)) == 0u); \
        if (dsc ? (x < y) : (x > y)) { KEYWR(i, y); KEYWR(ixj, x); } \
    } \
    __syncthreads(); \
} while (0)

#define REG_TAIL(D) do { \
    int seg = w << 8; \
    bool d = (D); \
    u64 e0 = KEYRD(seg + l); \
    u64 e1 = KEYRD(seg + 64 + l); \
    u64 e2 = KEYRD(seg + 128 + l); \
    u64 e3 = KEYRD(seg + 192 + l); \
    CE_PAIR(e0, e2, d); CE_PAIR(e1, e3, d); \
    CE_PAIR(e0, e1, d); CE_PAIR(e2, e3, d); \
    _Pragma("unroll") \
    for (int j = 32; j >= 1; j >>= 1) { \
        CE_SHFL(e0, j, d); CE_SHFL(e1, j, d); \
        CE_SHFL(e2, j, d); CE_SHFL(e3, j, d); \
    } \
    KEYWR(seg + l, e0); KEYWR(seg + 64 + l, e1); \
    KEYWR(seg + 128 + l, e2); KEYWR(seg + 192 + l, e3); \
    __syncthreads(); \
} while (0)

__global__ __launch_bounds__(512) void sort_kernel(
        const unsigned* __restrict__ cnt_blk,
        const u64* __restrict__ cand,
        const float* __restrict__ deltas,
        const float* __restrict__ im_info,
        float4* __restrict__ bxg,
        unsigned* __restrict__ m2arr,
        unsigned* __restrict__ okarr) {
    int b = blockIdx.x;
    __shared__ unsigned khi[SORT2];   // 8 KB
    __shared__ unsigned klo[SORT2];   // 8 KB
    __shared__ unsigned offs[BPB + 1];
    __shared__ unsigned ovfl;
    int tid = threadIdx.x;
    int l = tid & 63, w = tid >> 6;

    if (tid == 0) { ovfl = 0; offs[0] = 0; }
    __syncthreads();
    if (tid < BPB) {
        unsigned c = cnt_blk[b * BPB + tid];
        if (c > SLOTS) atomicOr(&ovfl, 1u);
        offs[tid + 1] = (c > SLOTS) ? SLOTS : c;
    }
    for (int i = tid; i < SORT2; i += 512) { khi[i] = 0u; klo[i] = 0u; }
    __syncthreads();
    if (tid == 0)
        for (int i = 1; i <= BPB; ++i) offs[i] += offs[i - 1];
    __syncthreads();
    unsigned m2 = offs[BPB];
    bool ok = (!ovfl) && (m2 >= 1) && (m2 <= SORT2);   // block-uniform

    if (ok) {
        for (int s = w; s < BPB; s += 8) {
            unsigned c = offs[s + 1] - offs[s];
            if ((unsigned)l < c) {
                u64 k = cand[(size_t)(b * BPB + s) * SLOTS + l];
                KEYWR(offs[s] + l, k);
            }
        }
    }
    __syncthreads();

    if (ok) {
        {
            int seg = w << 8;
            u64 e0 = KEYRD(seg + l);
            u64 e1 = KEYRD(seg + 64 + l);
            u64 e2 = KEYRD(seg + 128 + l);
            u64 e3 = KEYRD(seg + 192 + l);
            #pragma unroll
            for (int k = 2; k <= 32; k <<= 1) {
                bool d = ((l & k) == 0);
                #pragma unroll
                for (int j = k >> 1; j >= 1; j >>= 1) {
                    CE_SHFL(e0, j, d); CE_SHFL(e1, j, d);
                    CE_SHFL(e2, j, d); CE_SHFL(e3, j, d);
                }
            }
            #pragma unroll
            for (int j = 32; j >= 1; j >>= 1) {
                CE_SHFL(e0, j, true);  CE_SHFL(e1, j, false);
                CE_SHFL(e2, j, true);  CE_SHFL(e3, j, false);
            }
            CE_PAIR(e0, e1, true); CE_PAIR(e2, e3, false);
            #pragma unroll
            for (int j = 32; j >= 1; j >>= 1) {
                CE_SHFL(e0, j, true);  CE_SHFL(e1, j, true);
                CE_SHFL(e2, j, false); CE_SHFL(e3, j, false);
            }
            {
                bool d = ((w & 1) == 0);
                CE_PAIR(e0, e2, d); CE_PAIR(e1, e3, d);
                CE_PAIR(e0, e1, d); CE_PAIR(e2, e3, d);
                #pragma unroll
                for (int j = 32; j >= 1; j >>= 1) {
                    CE_SHFL(e0, j, d); CE_SHFL(e1, j, d);
                    CE_SHFL(e2, j, d); CE_SHFL(e3, j, d);
                }
            }
            KEYWR(seg + l, e0); KEYWR(seg + 64 + l, e1);
            KEYWR(seg + 128 + l, e2); KEYWR(seg + 192 + l, e3);
        }
        __syncthreads();
        LDS_PHASE(512, 256);                 REG_TAIL(((w & 2) == 0));
        LDS_PHASE(1024, 512); LDS_PHASE(1024, 256);  REG_TAIL(((w & 4) == 0));
        LDS_PHASE(2048, 1024); LDS_PHASE(2048, 512); LDS_PHASE(2048, 256);
        REG_TAIL(true);

        float wmax = im_info[b * 3 + 1] - 1.0f;
        float hmax = im_info[b * 3 + 0] - 1.0f;
        int mceil = (int)((m2 + 63u) & ~63u);
        for (int i = tid; i < mceil; i += 512) {
            float4 v;
            if (i < (int)m2) v = decode_box(~klo[i], deltas, b, wmax, hmax);
            else             v = make_float4(-3e9f, -3e9f, -3e9f, -3e9f);
            bxg[(size_t)b * SORT2 + i] = v;
        }
    }
    if (tid == 0) { m2arr[b] = m2; okarr[b] = ok ? 1u : 0u; }
}

// --- Pass 3: suppression bit-matrix incl. diagonal (WIDE: 512 blocks) --------
// Block (b, t): rows [64t, 64t+64), words w in [t, 32). Bit j of word w:
// IoU(row, 64w+j) > 0.7. Backward words unwritten (never consumed).
__global__ __launch_bounds__(256) void mask_kernel(
        const float4* __restrict__ bxg,
        const unsigned* __restrict__ m2arr,
        const unsigned* __restrict__ okarr,
        u64* __restrict__ mask) {
    int b = blockIdx.x >> 5;
    int t = blockIdx.x & 31;
    if (!okarr[b]) return;
    unsigned m2 = m2arr[b];
    if ((unsigned)(t * 64) >= m2) return;
    __shared__ float4 sb[SORT2];   // 32 KB
    __shared__ float  sa[SORT2];   //  8 KB
    int tid = threadIdx.x;
    int mceil = (int)((m2 + 63u) & ~63u);
    for (int i = tid; i < mceil; i += 256) {
        float4 v = bxg[(size_t)b * SORT2 + i];   // padded rows pre-filled by sort
        sb[i] = v;
        sa[i] = (v.z - v.x + 1.f) * (v.w - v.y + 1.f);
    }
    __syncthreads();
    int r = t * 64 + (tid >> 2);
    int q = tid & 3;
    float4 rb = sb[r];
    float  ra = sa[r];
    u64* mrow = mask + ((size_t)b * SORT2 + r) * NWORD;
    for (int w = t + q; w < NWORD; w += 4) {
        if (w * 64 >= mceil) break;
        u64 bits = 0;
        #pragma unroll 4
        for (int jj = 0; jj < 64; ++jj) {
            int j = w * 64 + jj;
            bits |= ((u64)(iou_over(rb, ra, sb[j], sa[j]) ? 1 : 0)) << jj;
        }
        mrow[w] = bits;
    }
}

// --- Pass 4: resolve with LDS double-buffered chunk prefetch + inline exact
//     fallback. Waves 1-7 prefetch chunk c+1's 64 mask rows (16 KB) while
//     wave 0 processes chunk c entirely from LDS. One barrier per chunk. ------
__global__ __launch_bounds__(512) void resolve_fb_kernel(
        const float4* __restrict__ bxg,
        const u64* __restrict__ mask,
        const unsigned* __restrict__ m2arr,
        const unsigned* __restrict__ okarr,
        const float* __restrict__ scores,
        const float* __restrict__ deltas,
        const float* __restrict__ im_info,
        float4* __restrict__ fbbox,
        float* __restrict__ out) {
    int b = blockIdx.x;
    int tid = threadIdx.x;
    int wv = tid >> 6;
    // smem: fast path rowbuf[2][64*NWORD] u64 = 32 KB; fb keys = 64 KB (aliased)
    __shared__ __align__(16) char smem[65536];
    __shared__ unsigned short kept_idx[POST_NMS];
    __shared__ unsigned nk_sh;
    __shared__ unsigned lh[256];
    __shared__ unsigned d8_sh, above_sh, tbin_sh, fbcnt;

    u64* rowbuf = (u64*)smem;            // [2][2048]

    bool okb = (okarr[b] != 0);
    int m2 = okb ? (int)m2arr[b] : 0;
    int nchunks = (m2 + 63) >> 6;
    const u64* mb = mask + (size_t)b * SORT2 * NWORD;
    if (tid == 0) nk_sh = 0;

    if (okb) {
        // prologue: stage chunk 0's rows (16 KB contiguous)
        for (int i = tid; i < 64 * NWORD; i += 512)
            rowbuf[i] = mb[i];
    }
    __syncthreads();

    if (okb) {
        int lane = tid & 63;
        int w32c = lane & 31;
        u64 S = 0;       // wave-0 lanes: OR of word w32c over kept rows so far
        int nk = 0;      // meaningful in wave 0 only
        int cur = 0;
        for (int c = 0; c < nchunks; ++c) {
            int nxt = cur ^ 1;
            if (wv > 0) {
                // waves 1-7: prefetch next chunk's rows into rowbuf[nxt]
                if (c + 1 < nchunks) {
                    const u64* src = mb + (size_t)(c + 1) * 64 * NWORD;
                    for (int i = tid - 64; i < 64 * NWORD; i += 448)
                        rowbuf[nxt * (64 * NWORD) + i] = src[i];
                }
            } else if (nk < POST_NMS) {
                // wave 0: greedy on chunk c from LDS
                int base = c * 64;
                int nvalid = min(64, m2 - base);
                u64* rc = rowbuf + cur * (64 * NWORD);
                u64 d = rc[lane * NWORD + c];          // own row's diag word
                unsigned wl0 = __builtin_amdgcn_readlane((unsigned)S, c);
                unsigned wh0 = __builtin_amdgcn_readlane((unsigned)(S >> 32), c);
                unsigned wl1 = __builtin_amdgcn_readlane((unsigned)S, c + 32);
                unsigned wh1 = __builtin_amdgcn_readlane((unsigned)(S >> 32), c + 32);
                u64 Sc = (((u64)wh0 << 32) | wl0) | (((u64)wh1 << 32) | wl1);
                u64 live = ~Sc;
                if (nvalid < 64) live &= (1ull << nvalid) - 1ull;
                u64 keptC = 0;
                while (live && nk < POST_NMS) {
                    int il = (int)__ffsll((long long)live) - 1;
                    unsigned dlo = __builtin_amdgcn_readlane((unsigned)d, il);
                    unsigned dhi = __builtin_amdgcn_readlane((unsigned)(d >> 32), il);
                    u64 drow = ((u64)dhi << 32) | dlo;
                    live &= ~drow;
                    live &= ~(1ull << il);
                    if (lane == 0) kept_idx[nk] = (unsigned short)(base + il);
                    keptC |= 1ull << il;
                    ++nk;
                }
                // S-update from LDS rows (each lane reads word w32c per kept)
                if (nk < POST_NMS && c + 1 < nchunks) {
                    long long kc = (long long)keptC;
                    while (kc) {
                        int s = (int)__ffsll(kc) - 1; kc &= kc - 1;
                        S |= rc[s * NWORD + w32c];
                    }
                }
                if (lane == 0) nk_sh = (unsigned)nk;
            }
            __syncthreads();
            cur = nxt;
        }
    }
    __syncthreads();

    unsigned nk = nk_sh;
    bool ok_final = okb && (nk == POST_NMS);   // block-uniform
    if (ok_final) {
        const float4* bx = bxg + (size_t)b * SORT2;
        for (int t = tid; t < POST_NMS; t += 512) {
            float4 kb = bx[kept_idx[t]];
            float* o = out + ((size_t)b * POST_NMS + t) * 5;
            o[0] = (float)b;
            o[1] = kb.x; o[2] = kb.y; o[3] = kb.z; o[4] = kb.w;
        }
        return;
    }

    // ---------------- exact fallback (in-block; verified R10/R11 body) -------
    u64* keys = (u64*)smem;   // 64 KB, overwrites rowbuf (fast path dead)
    __syncthreads();
    if (tid < 256) lh[tid] = 0;
    __syncthreads();
    for (int a = 0; a < A_NUM; ++a) {
        const float* p = scores + ((size_t)(b * 2 * A_NUM + A_NUM + a)) * K_FEAT;
        for (int k = tid; k < K_FEAT; k += 512)
            hist_add(lh, key_bits(p[k]) >> 24);
    }
    __syncthreads();
    if (tid == 0) {
        unsigned acc = 0; int d = 0;
        for (int i = 255; i >= 0; --i) {
            unsigned v = lh[i];
            if (acc + v >= PRE_NMS) { d = i; break; }
            acc += v;
        }
        d8_sh = (unsigned)d; above_sh = acc;
    }
    __syncthreads();
    unsigned dd = d8_sh;
    if (tid < 256) lh[tid] = 0;
    __syncthreads();
    for (int a = 0; a < A_NUM; ++a) {
        const float* p = scores + ((size_t)(b * 2 * A_NUM + A_NUM + a)) * K_FEAT;
        for (int k = tid; k < K_FEAT; k += 512) {
            unsigned u = key_bits(p[k]);
            if ((u >> 24) == dd) hist_add(lh, (u >> 16) & 0xFF);
        }
    }
    __syncthreads();
    if (tid == 0) {
        unsigned acc = above_sh; int d = 0;
        for (int i = 255; i >= 0; --i) {
            unsigned v = lh[i];
            if (acc + v >= PRE_NMS) { d = i; break; }
            acc += v;
        }
        tbin_sh = (dd << 8) | (unsigned)d;
        fbcnt = 0;
    }
    __syncthreads();
    unsigned tb = tbin_sh;
    for (int i = tid; i < CAP; i += 512) keys[i] = 0ULL;
    __syncthreads();
    for (int a = 0; a < A_NUM; ++a) {
        const float* p = scores + ((size_t)(b * 2 * A_NUM + A_NUM + a)) * K_FEAT;
        for (int k = tid; k < K_FEAT; k += 512) {
            unsigned u = key_bits(p[k]);
            if ((u >> 16) >= tb) {
                unsigned n = (unsigned)k * A_NUM + (unsigned)a;
                unsigned pos = atomicAdd(&fbcnt, 1u);
                if (pos < CAP) keys[pos] = ((u64)u << 32) | (unsigned)(~n);
            }
        }
    }
    __syncthreads();
    for (unsigned k = 2; k <= CAP; k <<= 1) {
        for (unsigned j = k >> 1; j > 0; j >>= 1) {
            #pragma unroll
            for (int pp = 0; pp < 8; ++pp) {
                unsigned p = (unsigned)tid + (unsigned)pp * 512u;
                unsigned i = ((p & ~(j - 1)) << 1) | (p & (j - 1));
                unsigned ixj = i | j;
                u64 x = keys[i], y = keys[ixj];
                bool desc = ((i & k) == 0);
                if (desc ? (x < y) : (x > y)) { keys[i] = y; keys[ixj] = x; }
            }
            __syncthreads();
        }
    }
    float wmax = im_info[b * 3 + 1] - 1.0f;
    float hmax = im_info[b * 3 + 0] - 1.0f;
    for (int i = tid; i < PRE_NMS; i += 512) {
        unsigned n = ~(unsigned)(keys[i] & 0xFFFFFFFFull);
        float4 box = make_float4(0.f, 0.f, 0.f, 0.f);
        if (n < N_ANCH) box = decode_box(n, deltas, b, wmax, hmax);
        fbbox[(size_t)b * PRE_NMS + i] = box;
    }
    __syncthreads();
    if (tid >= 64) return;
    int lane = tid;
    float4 k0, k1v, k2v, k3v, k4v;
    float a0 = 1.f, a1 = 1.f, a2 = 1.f, a3 = 1.f, a4 = 1.f;
    k0 = k1v = k2v = k3v = k4v = make_float4(0.f, 0.f, 0.f, 0.f);
    const float4* bb = fbbox + (size_t)b * PRE_NMS;
    int nk2 = 0;
    for (int i = 0; i < PRE_NMS && nk2 < POST_NMS; ++i) {
        float4 cur = bb[i];
        float ca = (cur.z - cur.x + 1.f) * (cur.w - cur.y + 1.f);
        bool s = false;
        if (nk2 > 0)   { bool v = lane < nk2;       s |= v && iou_over(k0,  a0, cur, ca); }
        if (nk2 > 64)  { bool v = 64 + lane < nk2;  s |= v && iou_over(k1v, a1, cur, ca); }
        if (nk2 > 128) { bool v = 128 + lane < nk2; s |= v && iou_over(k2v, a2, cur, ca); }
        if (nk2 > 192) { bool v = 192 + lane < nk2; s |= v && iou_over(k3v, a3, cur, ca); }
        if (nk2 > 256) { bool v = 256 + lane < nk2; s |= v && iou_over(k4v, a4, cur, ca); }
        if (!__any(s)) {
            int r = nk2 >> 6;
            if (lane == (nk2 & 63)) {
                if      (r == 0) { k0  = cur; a0 = ca; }
                else if (r == 1) { k1v = cur; a1 = ca; }
                else if (r == 2) { k2v = cur; a2 = ca; }
                else if (r == 3) { k3v = cur; a3 = ca; }
                else             { k4v = cur; a4 = ca; }
            }
            if (lane == 0) {
                float* o = out + ((size_t)b * POST_NMS + nk2) * 5;
                o[0] = (float)b;
                o[1] = cur.x; o[2] = cur.y; o[3] = cur.z; o[4] = cur.w;
            }
            ++nk2;
        }
    }
    for (int t = nk2 + lane; t < POST_NMS; t += 64) {
        float* o = out + ((size_t)b * POST_NMS + t) * 5;
        o[0] = (float)b;
        o[1] = 0.f; o[2] = 0.f; o[3] = 0.f; o[4] = 0.f;
    }
}

extern "C" void kernel_launch(void* const* d_in, const int* in_sizes, int n_in,
                              void* d_out, int out_size, void* d_ws, size_t ws_size,
                              hipStream_t stream) {
    const float* scores  = (const float*)d_in[0];
    const float* deltas  = (const float*)d_in[1];
    const float* im_info = (const float*)d_in[2];
    float* out = (float*)d_out;

    // workspace layout (everything written-before-read each call; no init pass)
    size_t off = 0;
    unsigned* cnt_blk = (unsigned*)((char*)d_ws + off);          // 1296 u32
    off += (size_t)BATCH * BPB * 4;
    off = (off + 255) & ~(size_t)255;
    u64* cand = (u64*)((char*)d_ws + off);                       // 648 KB
    off += (size_t)BATCH * BPB * SLOTS * 8;
    off = (off + 255) & ~(size_t)255;
    unsigned* m2arr = (unsigned*)((char*)d_ws + off);            // 16 u32
    off += (size_t)BATCH * 4;
    off = (off + 255) & ~(size_t)255;
    unsigned* okarr = (unsigned*)((char*)d_ws + off);            // 16 u32
    off += (size_t)BATCH * 4;
    off = (off + 255) & ~(size_t)255;
    float4* bxg = (float4*)((char*)d_ws + off);                  // 512 KB
    off += (size_t)BATCH * SORT2 * 16;
    off = (off + 255) & ~(size_t)255;
    u64* mask = (u64*)((char*)d_ws + off);                       // 8 MB
    off += (size_t)BATCH * SORT2 * NWORD * 8;
    off = (off + 255) & ~(size_t)255;
    float4* fbbox = (float4*)((char*)d_ws + off);                // 1.5 MB (fallback)

    compact_kernel   <<<BATCH * BPB, 256, 0, stream>>>(scores, cnt_blk, cand);
    sort_kernel      <<<BATCH, 512, 0, stream>>>(cnt_blk, cand, deltas, im_info,
                                                 bxg, m2arr, okarr);
    mask_kernel      <<<BATCH * 32, 256, 0, stream>>>(bxg, m2arr, okarr, mask);
    resolve_fb_kernel<<<BATCH, 512, 0, stream>>>(bxg, mask, m2arr, okarr,
                                                 scores, deltas, im_info,
                                                 fbbox, out);
}

// Round 16
// 105.889 us; speedup vs baseline: 1.2726x; 1.2726x over previous
//
#include <hip/hip_runtime.h>
#include <stdint.h>

// Problem constants (fixed by setup_inputs: B=16, A=9, H=W=192)
#define A_NUM    9
#define W_FEAT   192
#define H_FEAT   192
#define K_FEAT   (W_FEAT * H_FEAT)     // 36864 positions
#define N_ANCH   (K_FEAT * A_NUM)      // 331776 anchors per batch
#define BATCH    16
#define PRE_NMS  6000
#define POST_NMS 300
#define CAP      8192                  // fallback candidate buffer
#define CHUNK    4096                  // elements per compact chunk
#define BPB      (N_ANCH / CHUNK)      // 81 chunks per batch
#define CPA      (K_FEAT / CHUNK)      // 9 chunks per anchor-plane
#define SORT2    2048                  // fast-path sort size
#define NWORD    (SORT2 / 64)          // 32 mask words per row
#define SLOTS    64                    // per-chunk cand slots (mean 16, 12 sigma)

// Static fast-path threshold: key16 >= 0xBF7F <=> score >= 0.99609375 (p = 1/256
// exactly for Uniform[0,1)). E[cnt]=1296/batch, sigma=36 — matches the dynamic
// threshold bin of all passing rounds R3-R15. Any distribution shift is caught
// dynamically (slot overflow / <300 keeps) -> in-block exact fallback.
#define T2KEY    0xBF7Fu

typedef unsigned long long u64;

// py-faster-rcnn standard anchors (base 16, ratios .5/1/2, scales 8/16/32)
__constant__ float c_anchors[A_NUM][4] = {
    { -84.f,  -40.f,  99.f,  55.f},
    {-176.f,  -88.f, 191.f, 103.f},
    {-360.f, -184.f, 375.f, 199.f},
    { -56.f,  -56.f,  71.f,  71.f},
    {-120.f, -120.f, 135.f, 135.f},
    {-248.f, -248.f, 263.f, 263.f},
    { -36.f,  -80.f,  51.f,  95.f},
    { -80.f, -168.f,  95.f, 183.f},
    {-168.f, -344.f, 183.f, 359.f},
};

__device__ __forceinline__ unsigned key_bits(float s) {
    unsigned ub = __float_as_uint(s);
    return (ub & 0x80000000u) ? ~ub : (ub | 0x80000000u);
}

__device__ __forceinline__ const float* chunk_ptr(const float* scores, int blk,
                                                  int& b, int& a, int& koff) {
    b = blk / BPB;
    int chunk = blk - b * BPB;
    a = chunk / CPA;
    koff = (chunk - a * CPA) * CHUNK;
    return scores + ((size_t)(b * 2 * A_NUM + A_NUM + a)) * K_FEAT + koff;
}

// ballot-aggregated LDS histogram add: one atomic per distinct bin per wave
__device__ __forceinline__ void hist_add(unsigned* lh, unsigned bin) {
    unsigned long long peers = __ballot(1);
    #pragma unroll
    for (int bit = 0; bit < 8; ++bit) {
        unsigned long long vote = __ballot((bin >> bit) & 1);
        peers &= ((bin >> bit) & 1) ? vote : ~vote;
    }
    int lane = threadIdx.x & 63;
    if (lane == (int)(__ffsll((long long)peers) - 1))
        atomicAdd(&lh[bin], (unsigned)__popcll(peers));
}

__device__ __forceinline__ float4 decode_box(unsigned n, const float* __restrict__ deltas,
                                             int b, float wmax, float hmax) {
    unsigned kk = n / A_NUM, a = n - kk * A_NUM;
    unsigned hh = kk / W_FEAT, ww = kk - hh * W_FEAT;
    size_t dbase = ((size_t)(b * 4 * A_NUM + 4 * a)) * K_FEAT + kk;
    float dx = deltas[dbase];
    float dy = deltas[dbase + (size_t)K_FEAT];
    float dw = deltas[dbase + (size_t)2 * K_FEAT];
    float dh = deltas[dbase + (size_t)3 * K_FEAT];
    float ax1 = c_anchors[a][0] + ww * 16.0f;
    float ay1 = c_anchors[a][1] + hh * 16.0f;
    float ax2 = c_anchors[a][2] + ww * 16.0f;
    float ay2 = c_anchors[a][3] + hh * 16.0f;
    float waf = ax2 - ax1 + 1.0f, haf = ay2 - ay1 + 1.0f;
    float cx = ax1 + 0.5f * waf, cy = ay1 + 0.5f * haf;
    float pcx = dx * waf + cx, pcy = dy * haf + cy;
    float pw = expf(dw) * waf, ph = expf(dh) * haf;
    float4 box;
    box.x = fminf(fmaxf(pcx - 0.5f * pw, 0.f), wmax);
    box.y = fminf(fmaxf(pcy - 0.5f * ph, 0.f), hmax);
    box.z = fminf(fmaxf(pcx + 0.5f * pw, 0.f), wmax);
    box.w = fminf(fmaxf(pcy + 0.5f * ph, 0.f), hmax);
    return box;
}

// IoU(a, c) > 0.7 — identical algebra everywhere (bit-identical decisions)
__device__ __forceinline__ bool iou_over(float4 a, float aa, float4 c, float ca) {
    float xx1 = fmaxf(a.x, c.x), yy1 = fmaxf(a.y, c.y);
    float xx2 = fminf(a.z, c.z), yy2 = fminf(a.w, c.w);
    float iw = fmaxf(xx2 - xx1 + 1.f, 0.f);
    float ih = fmaxf(yy2 - yy1 + 1.f, 0.f);
    float inter = iw * ih;
    return inter > 0.7f * (aa + ca - inter);
}

__device__ __forceinline__ u64 shflxor64(u64 v, int j) {
    unsigned lo = (unsigned)v, hi = (unsigned)(v >> 32);
    lo = __shfl_xor(lo, j, 64);
    hi = __shfl_xor(hi, j, 64);
    return ((u64)hi << 32) | lo;
}

// --- Pass 1: compact candidates >= T2KEY to fixed per-block slots ------------
// Full-overwrite (count + slots) => no init kernel, no global atomics needed.
__global__ __launch_bounds__(256) void compact_kernel(
        const float* __restrict__ scores,
        unsigned* __restrict__ cnt_blk,
        u64* __restrict__ cand) {
    __shared__ u64 sbuf[256];
    __shared__ unsigned scount;
    int tid = threadIdx.x;
    if (tid == 0) scount = 0;
    __syncthreads();
    int b, a, koff;
    const float* p = chunk_ptr(scores, blockIdx.x, b, a, koff);
    const float4* p4 = (const float4*)p;
    #pragma unroll
    for (int it = 0; it < CHUNK / 1024; ++it) {
        float4 v = p4[it * 256 + tid];
        unsigned e0 = (unsigned)(koff + (it * 256 + tid) * 4);
        float vv[4] = {v.x, v.y, v.z, v.w};
        #pragma unroll
        for (int j = 0; j < 4; ++j) {
            unsigned ub = key_bits(vv[j]);
            if ((ub >> 16) >= T2KEY) {
                unsigned n = (e0 + j) * A_NUM + a;
                unsigned pos = atomicAdd(&scount, 1u);
                if (pos < 256)
                    sbuf[pos] = ((u64)ub << 32) | (unsigned)(~n);
            }
        }
    }
    __syncthreads();
    unsigned c = scount;
    if (tid == 0) cnt_blk[blockIdx.x] = c;   // true count (overflow detected later)
    unsigned cw = c < SLOTS ? c : SLOTS;
    if (tid < cw) cand[(size_t)blockIdx.x * SLOTS + tid] = sbuf[tid];
}

// --- Pass 2: gather + hybrid register/LDS bitonic sort + decode -> bxg -------
#define KEYRD(I)  ((((u64)khi[(I)]) << 32) | klo[(I)])
#define KEYWR(I, V) do { khi[(I)] = (unsigned)((V) >> 32); klo[(I)] = (unsigned)(V); } while (0)

#define CE_SHFL(E, J, DESC) do { \
    u64 _v = shflxor64((E), (J)); \
    bool _kmax = ((DESC) == ((l & (J)) == 0)); \
    (E) = _kmax ? ((E) > _v ? (E) : _v) : ((E) < _v ? (E) : _v); \
} while (0)

#define CE_PAIR(A, B, DESC) do { \
    u64 _mx = (A) > (B) ? (A) : (B); \
    u64 _mn = (A) > (B) ? (B) : (A); \
    if (DESC) { (A) = _mx; (B) = _mn; } else { (A) = _mn; (B) = _mx; } \
} while (0)

#define LDS_PHASE(K, J) do { \
    _Pragma("unroll") \
    for (int pp = 0; pp < 2; ++pp) { \
        unsigned p = (unsigned)tid + (unsigned)pp * 512u; \
        unsigned i = ((p & ~((unsigned)(J) - 1u)) << 1) | (p & ((unsigned)(J) - 1u)); \
        unsigned ixj = i | (unsigned)(J); \
        u64 x = KEYRD(i), y = KEYRD(ixj); \
        bool dsc = ((i & (unsigned)(K)) == 0u); \
        if (dsc ? (x < y) : (x > y)) { KEYWR(i, y); KEYWR(ixj, x); } \
    } \
    __syncthreads(); \
} while (0)

#define REG_TAIL(D) do { \
    int seg = w << 8; \
    bool d = (D); \
    u64 e0 = KEYRD(seg + l); \
    u64 e1 = KEYRD(seg + 64 + l); \
    u64 e2 = KEYRD(seg + 128 + l); \
    u64 e3 = KEYRD(seg + 192 + l); \
    CE_PAIR(e0, e2, d); CE_PAIR(e1, e3, d); \
    CE_PAIR(e0, e1, d); CE_PAIR(e2, e3, d); \
    _Pragma("unroll") \
    for (int j = 32; j >= 1; j >>= 1) { \
        CE_SHFL(e0, j, d); CE_SHFL(e1, j, d); \
        CE_SHFL(e2, j, d); CE_SHFL(e3, j, d); \
    } \
    KEYWR(seg + l, e0); KEYWR(seg + 64 + l, e1); \
    KEYWR(seg + 128 + l, e2); KEYWR(seg + 192 + l, e3); \
    __syncthreads(); \
} while (0)

__global__ __launch_bounds__(512) void sort_kernel(
        const unsigned* __restrict__ cnt_blk,
        const u64* __restrict__ cand,
        const float* __restrict__ deltas,
        const float* __restrict__ im_info,
        float4* __restrict__ bxg,
        unsigned* __restrict__ m2arr,
        unsigned* __restrict__ okarr) {
    int b = blockIdx.x;
    __shared__ unsigned khi[SORT2];   // 8 KB
    __shared__ unsigned klo[SORT2];   // 8 KB
    __shared__ unsigned offs[BPB + 1];
    __shared__ unsigned ovfl;
    int tid = threadIdx.x;
    int l = tid & 63, w = tid >> 6;

    if (tid == 0) { ovfl = 0; offs[0] = 0; }
    __syncthreads();
    if (tid < BPB) {
        unsigned c = cnt_blk[b * BPB + tid];
        if (c > SLOTS) atomicOr(&ovfl, 1u);
        offs[tid + 1] = (c > SLOTS) ? SLOTS : c;
    }
    for (int i = tid; i < SORT2; i += 512) { khi[i] = 0u; klo[i] = 0u; }
    __syncthreads();
    if (tid == 0)
        for (int i = 1; i <= BPB; ++i) offs[i] += offs[i - 1];
    __syncthreads();
    unsigned m2 = offs[BPB];
    bool ok = (!ovfl) && (m2 >= 1) && (m2 <= SORT2);   // block-uniform

    if (ok) {
        for (int s = w; s < BPB; s += 8) {
            unsigned c = offs[s + 1] - offs[s];
            if ((unsigned)l < c) {
                u64 k = cand[(size_t)(b * BPB + s) * SLOTS + l];
                KEYWR(offs[s] + l, k);
            }
        }
    }
    __syncthreads();

    if (ok) {
        {
            int seg = w << 8;
            u64 e0 = KEYRD(seg + l);
            u64 e1 = KEYRD(seg + 64 + l);
            u64 e2 = KEYRD(seg + 128 + l);
            u64 e3 = KEYRD(seg + 192 + l);
            #pragma unroll
            for (int k = 2; k <= 32; k <<= 1) {
                bool d = ((l & k) == 0);
                #pragma unroll
                for (int j = k >> 1; j >= 1; j >>= 1) {
                    CE_SHFL(e0, j, d); CE_SHFL(e1, j, d);
                    CE_SHFL(e2, j, d); CE_SHFL(e3, j, d);
                }
            }
            #pragma unroll
            for (int j = 32; j >= 1; j >>= 1) {
                CE_SHFL(e0, j, true);  CE_SHFL(e1, j, false);
                CE_SHFL(e2, j, true);  CE_SHFL(e3, j, false);
            }
            CE_PAIR(e0, e1, true); CE_PAIR(e2, e3, false);
            #pragma unroll
            for (int j = 32; j >= 1; j >>= 1) {
                CE_SHFL(e0, j, true);  CE_SHFL(e1, j, true);
                CE_SHFL(e2, j, false); CE_SHFL(e3, j, false);
            }
            {
                bool d = ((w & 1) == 0);
                CE_PAIR(e0, e2, d); CE_PAIR(e1, e3, d);
                CE_PAIR(e0, e1, d); CE_PAIR(e2, e3, d);
                #pragma unroll
                for (int j = 32; j >= 1; j >>= 1) {
                    CE_SHFL(e0, j, d); CE_SHFL(e1, j, d);
                    CE_SHFL(e2, j, d); CE_SHFL(e3, j, d);
                }
            }
            KEYWR(seg + l, e0); KEYWR(seg + 64 + l, e1);
            KEYWR(seg + 128 + l, e2); KEYWR(seg + 192 + l, e3);
        }
        __syncthreads();
        LDS_PHASE(512, 256);                 REG_TAIL(((w & 2) == 0));
        LDS_PHASE(1024, 512); LDS_PHASE(1024, 256);  REG_TAIL(((w & 4) == 0));
        LDS_PHASE(2048, 1024); LDS_PHASE(2048, 512); LDS_PHASE(2048, 256);
        REG_TAIL(true);

        float wmax = im_info[b * 3 + 1] - 1.0f;
        float hmax = im_info[b * 3 + 0] - 1.0f;
        int mceil = (int)((m2 + 63u) & ~63u);
        for (int i = tid; i < mceil; i += 512) {
            float4 v;
            if (i < (int)m2) v = decode_box(~klo[i], deltas, b, wmax, hmax);
            else             v = make_float4(-3e9f, -3e9f, -3e9f, -3e9f);
            bxg[(size_t)b * SORT2 + i] = v;
        }
    }
    if (tid == 0) { m2arr[b] = m2; okarr[b] = ok ? 1u : 0u; }
}

// --- Pass 3: suppression bit-matrix incl. diagonal (WIDE: 512 blocks) --------
// Block (b, t): rows [64t, 64t+64), words w in [t, 32). Bit j of word w:
// IoU(row, 64w+j) > 0.7. Backward words unwritten (never consumed).
__global__ __launch_bounds__(256) void mask_kernel(
        const float4* __restrict__ bxg,
        const unsigned* __restrict__ m2arr,
        const unsigned* __restrict__ okarr,
        u64* __restrict__ mask) {
    int b = blockIdx.x >> 5;
    int t = blockIdx.x & 31;
    if (!okarr[b]) return;
    unsigned m2 = m2arr[b];
    if ((unsigned)(t * 64) >= m2) return;
    __shared__ float4 sb[SORT2];   // 32 KB
    __shared__ float  sa[SORT2];   //  8 KB
    int tid = threadIdx.x;
    int mceil = (int)((m2 + 63u) & ~63u);
    for (int i = tid; i < mceil; i += 256) {
        float4 v = bxg[(size_t)b * SORT2 + i];   // padded rows pre-filled by sort
        sb[i] = v;
        sa[i] = (v.z - v.x + 1.f) * (v.w - v.y + 1.f);
    }
    __syncthreads();
    int r = t * 64 + (tid >> 2);
    int q = tid & 3;
    float4 rb = sb[r];
    float  ra = sa[r];
    u64* mrow = mask + ((size_t)b * SORT2 + r) * NWORD;
    for (int w = t + q; w < NWORD; w += 4) {
        if (w * 64 >= mceil) break;
        u64 bits = 0;
        #pragma unroll 4
        for (int jj = 0; jj < 64; ++jj) {
            int j = w * 64 + jj;
            bits |= ((u64)(iou_over(rb, ra, sb[j], sa[j]) ? 1 : 0)) << jj;
        }
        mrow[w] = bits;
    }
}

// --- Pass 4: resolve (wave 0, readlane core, 16-row S-rounds) + inline exact
//     fallback (runs only when the fast path fails; never on bench data) -----
__global__ __launch_bounds__(512) void resolve_fb_kernel(
        const float4* __restrict__ bxg,
        const u64* __restrict__ mask,
        const unsigned* __restrict__ m2arr,
        const unsigned* __restrict__ okarr,
        const float* __restrict__ scores,
        const float* __restrict__ deltas,
        const float* __restrict__ im_info,
        float4* __restrict__ fbbox,
        float* __restrict__ out) {
    int b = blockIdx.x;
    int tid = threadIdx.x;
    __shared__ unsigned short kept_idx[POST_NMS];
    __shared__ unsigned nk_sh;
    __shared__ unsigned lh[256];
    __shared__ unsigned d8_sh, above_sh, tbin_sh, fbcnt;
    __shared__ u64 keys[CAP];   // 64 KB — used only by the fallback path

    bool okb = (okarr[b] != 0);
    if (tid == 0) nk_sh = 0;
    __syncthreads();

    if (okb && tid < 64) {
        int lane = tid;
        int m2 = (int)m2arr[b];
        const u64* mb = mask + (size_t)b * SORT2 * NWORD;
        u64 S = 0;
        int w32 = lane & 31;
        bool hiHalf = lane >= 32;
        int nchunks = (m2 + 63) >> 6;
        u64 dpre = mb[(size_t)lane * NWORD + 0];
        int nk = 0;
        for (int c = 0; c < nchunks && nk < POST_NMS; ++c) {
            int base = c * 64;
            int nvalid = min(64, m2 - base);
            u64 d = dpre;
            if (c + 1 < nchunks)
                dpre = mb[(size_t)(base + 64 + lane) * NWORD + (c + 1)];
            unsigned wl0 = __builtin_amdgcn_readlane((unsigned)S, c);
            unsigned wh0 = __builtin_amdgcn_readlane((unsigned)(S >> 32), c);
            unsigned wl1 = __builtin_amdgcn_readlane((unsigned)S, c + 32);
            unsigned wh1 = __builtin_amdgcn_readlane((unsigned)(S >> 32), c + 32);
            u64 Sc = (((u64)wh0 << 32) | wl0) | (((u64)wh1 << 32) | wl1);
            u64 live = ~Sc;
            if (nvalid < 64) live &= (1ull << nvalid) - 1ull;
            u64 keptC = 0;
            while (live && nk < POST_NMS) {
                int il = (int)__ffsll((long long)live) - 1;
                unsigned dlo = __builtin_amdgcn_readlane((unsigned)d, il);
                unsigned dhi = __builtin_amdgcn_readlane((unsigned)(d >> 32), il);
                u64 drow = ((u64)dhi << 32) | dlo;
                live &= ~drow;
                live &= ~(1ull << il);
                if (lane == 0) kept_idx[nk] = (unsigned short)(base + il);
                keptC |= 1ull << il;
                ++nk;
            }
            // cross-chunk S update: 16 rows/round, parity-split (8 loads/lane)
            if (nk < POST_NMS && c + 1 < nchunks && keptC) {
                long long kc = (long long)keptC;
                while (kc) {
                    int r0  = (int)__ffsll(kc) - 1; kc &= kc - 1;
                    int r1  = (int)__ffsll(kc) - 1; kc &= kc - 1;
                    int r2  = (int)__ffsll(kc) - 1; kc &= kc - 1;
                    int r3  = (int)__ffsll(kc) - 1; kc &= kc - 1;
                    int r4  = (int)__ffsll(kc) - 1; kc &= kc - 1;
                    int r5  = (int)__ffsll(kc) - 1; kc &= kc - 1;
                    int r6  = (int)__ffsll(kc) - 1; kc &= kc - 1;
                    int r7  = (int)__ffsll(kc) - 1; kc &= kc - 1;
                    int r8  = (int)__ffsll(kc) - 1; kc &= kc - 1;
                    int r9  = (int)__ffsll(kc) - 1; kc &= kc - 1;
                    int r10 = (int)__ffsll(kc) - 1; kc &= kc - 1;
                    int r11 = (int)__ffsll(kc) - 1; kc &= kc - 1;
                    int r12 = (int)__ffsll(kc) - 1; kc &= kc - 1;
                    int r13 = (int)__ffsll(kc) - 1; kc &= kc - 1;
                    int r14 = (int)__ffsll(kc) - 1; kc &= kc - 1;
                    int r15 = (int)__ffsll(kc) - 1; kc &= kc - 1;
                    int s0 = hiHalf ? r1  : r0;
                    int s1 = hiHalf ? r3  : r2;
                    int s2 = hiHalf ? r5  : r4;
                    int s3 = hiHalf ? r7  : r6;
                    int s4 = hiHalf ? r9  : r8;
                    int s5 = hiHalf ? r11 : r10;
                    int s6 = hiHalf ? r13 : r12;
                    int s7 = hiHalf ? r15 : r14;
                    u64 a0 = 0, a1 = 0, a2 = 0, a3 = 0;
                    u64 a4 = 0, a5 = 0, a6 = 0, a7 = 0;
                    if (s0 >= 0) a0 = mb[(size_t)(base + s0) * NWORD + w32];
                    if (s1 >= 0) a1 = mb[(size_t)(base + s1) * NWORD + w32];
                    if (s2 >= 0) a2 = mb[(size_t)(base + s2) * NWORD + w32];
                    if (s3 >= 0) a3 = mb[(size_t)(base + s3) * NWORD + w32];
                    if (s4 >= 0) a4 = mb[(size_t)(base + s4) * NWORD + w32];
                    if (s5 >= 0) a5 = mb[(size_t)(base + s5) * NWORD + w32];
                    if (s6 >= 0) a6 = mb[(size_t)(base + s6) * NWORD + w32];
                    if (s7 >= 0) a7 = mb[(size_t)(base + s7) * NWORD + w32];
                    S |= (a0 | a1) | (a2 | a3) | (a4 | a5) | (a6 | a7);
                }
            }
        }
        if (lane == 0) nk_sh = (unsigned)nk;
    }
    __syncthreads();

    unsigned nk = nk_sh;
    bool ok_final = okb && (nk == POST_NMS);   // block-uniform
    if (ok_final) {
        const float4* bx = bxg + (size_t)b * SORT2;
        for (int t = tid; t < POST_NMS; t += 512) {
            float4 kb = bx[kept_idx[t]];
            float* o = out + ((size_t)b * POST_NMS + t) * 5;
            o[0] = (float)b;
            o[1] = kb.x; o[2] = kb.y; o[3] = kb.z; o[4] = kb.w;
        }
        return;
    }

    // ---------------- exact fallback (in-block; R10 fb_kernel body) ----------
    if (tid < 256) lh[tid] = 0;
    __syncthreads();
    for (int a = 0; a < A_NUM; ++a) {
        const float* p = scores + ((size_t)(b * 2 * A_NUM + A_NUM + a)) * K_FEAT;
        for (int k = tid; k < K_FEAT; k += 512)
            hist_add(lh, key_bits(p[k]) >> 24);
    }
    __syncthreads();
    if (tid == 0) {
        unsigned acc = 0; int d = 0;
        for (int i = 255; i >= 0; --i) {
            unsigned v = lh[i];
            if (acc + v >= PRE_NMS) { d = i; break; }
            acc += v;
        }
        d8_sh = (unsigned)d; above_sh = acc;
    }
    __syncthreads();
    unsigned dd = d8_sh;
    if (tid < 256) lh[tid] = 0;
    __syncthreads();
    for (int a = 0; a < A_NUM; ++a) {
        const float* p = scores + ((size_t)(b * 2 * A_NUM + A_NUM + a)) * K_FEAT;
        for (int k = tid; k < K_FEAT; k += 512) {
            unsigned u = key_bits(p[k]);
            if ((u >> 24) == dd) hist_add(lh, (u >> 16) & 0xFF);
        }
    }
    __syncthreads();
    if (tid == 0) {
        unsigned acc = above_sh; int d = 0;
        for (int i = 255; i >= 0; --i) {
            unsigned v = lh[i];
            if (acc + v >= PRE_NMS) { d = i; break; }
            acc += v;
        }
        tbin_sh = (dd << 8) | (unsigned)d;
        fbcnt = 0;
    }
    __syncthreads();
    unsigned tb = tbin_sh;
    for (int i = tid; i < CAP; i += 512) keys[i] = 0ULL;
    __syncthreads();
    for (int a = 0; a < A_NUM; ++a) {
        const float* p = scores + ((size_t)(b * 2 * A_NUM + A_NUM + a)) * K_FEAT;
        for (int k = tid; k < K_FEAT; k += 512) {
            unsigned u = key_bits(p[k]);
            if ((u >> 16) >= tb) {
                unsigned n = (unsigned)k * A_NUM + (unsigned)a;
                unsigned pos = atomicAdd(&fbcnt, 1u);
                if (pos < CAP) keys[pos] = ((u64)u << 32) | (unsigned)(~n);
            }
        }
    }
    __syncthreads();
    for (unsigned k = 2; k <= CAP; k <<= 1) {
        for (unsigned j = k >> 1; j > 0; j >>= 1) {
            #pragma unroll
            for (int pp = 0; pp < 8; ++pp) {
                unsigned p = (unsigned)tid + (unsigned)pp * 512u;
                unsigned i = ((p & ~(j - 1)) << 1) | (p & (j - 1));
                unsigned ixj = i | j;
                u64 x = keys[i], y = keys[ixj];
                bool desc = ((i & k) == 0);
                if (desc ? (x < y) : (x > y)) { keys[i] = y; keys[ixj] = x; }
            }
            __syncthreads();
        }
    }
    float wmax = im_info[b * 3 + 1] - 1.0f;
    float hmax = im_info[b * 3 + 0] - 1.0f;
    for (int i = tid; i < PRE_NMS; i += 512) {
        unsigned n = ~(unsigned)(keys[i] & 0xFFFFFFFFull);
        float4 box = make_float4(0.f, 0.f, 0.f, 0.f);
        if (n < N_ANCH) box = decode_box(n, deltas, b, wmax, hmax);
        fbbox[(size_t)b * PRE_NMS + i] = box;
    }
    __syncthreads();
    if (tid >= 64) return;
    int lane = tid;
    float4 k0, k1v, k2v, k3v, k4v;
    float a0 = 1.f, a1 = 1.f, a2 = 1.f, a3 = 1.f, a4 = 1.f;
    k0 = k1v = k2v = k3v = k4v = make_float4(0.f, 0.f, 0.f, 0.f);
    const float4* bb = fbbox + (size_t)b * PRE_NMS;
    int nk2 = 0;
    for (int i = 0; i < PRE_NMS && nk2 < POST_NMS; ++i) {
        float4 cur = bb[i];
        float ca = (cur.z - cur.x + 1.f) * (cur.w - cur.y + 1.f);
        bool s = false;
        if (nk2 > 0)   { bool v = lane < nk2;       s |= v && iou_over(k0,  a0, cur, ca); }
        if (nk2 > 64)  { bool v = 64 + lane < nk2;  s |= v && iou_over(k1v, a1, cur, ca); }
        if (nk2 > 128) { bool v = 128 + lane < nk2; s |= v && iou_over(k2v, a2, cur, ca); }
        if (nk2 > 192) { bool v = 192 + lane < nk2; s |= v && iou_over(k3v, a3, cur, ca); }
        if (nk2 > 256) { bool v = 256 + lane < nk2; s |= v && iou_over(k4v, a4, cur, ca); }
        if (!__any(s)) {
            int r = nk2 >> 6;
            if (lane == (nk2 & 63)) {
                if      (r == 0) { k0  = cur; a0 = ca; }
                else if (r == 1) { k1v = cur; a1 = ca; }
                else if (r == 2) { k2v = cur; a2 = ca; }
                else if (r == 3) { k3v = cur; a3 = ca; }
                else             { k4v = cur; a4 = ca; }
            }
            if (lane == 0) {
                float* o = out + ((size_t)b * POST_NMS + nk2) * 5;
                o[0] = (float)b;
                o[1] = cur.x; o[2] = cur.y; o[3] = cur.z; o[4] = cur.w;
            }
            ++nk2;
        }
    }
    for (int t = nk2 + lane; t < POST_NMS; t += 64) {
        float* o = out + ((size_t)b * POST_NMS + t) * 5;
        o[0] = (float)b;
        o[1] = 0.f; o[2] = 0.f; o[3] = 0.f; o[4] = 0.f;
    }
}

extern "C" void kernel_launch(void* const* d_in, const int* in_sizes, int n_in,
                              void* d_out, int out_size, void* d_ws, size_t ws_size,
                              hipStream_t stream) {
    const float* scores  = (const float*)d_in[0];
    const float* deltas  = (const float*)d_in[1];
    const float* im_info = (const float*)d_in[2];
    float* out = (float*)d_out;

    // workspace layout (everything written-before-read each call; no init pass)
    size_t off = 0;
    unsigned* cnt_blk = (unsigned*)((char*)d_ws + off);          // 1296 u32
    off += (size_t)BATCH * BPB * 4;
    off = (off + 255) & ~(size_t)255;
    u64* cand = (u64*)((char*)d_ws + off);                       // 648 KB
    off += (size_t)BATCH * BPB * SLOTS * 8;
    off = (off + 255) & ~(size_t)255;
    unsigned* m2arr = (unsigned*)((char*)d_ws + off);            // 16 u32
    off += (size_t)BATCH * 4;
    off = (off + 255) & ~(size_t)255;
    unsigned* okarr = (unsigned*)((char*)d_ws + off);            // 16 u32
    off += (size_t)BATCH * 4;
    off = (off + 255) & ~(size_t)255;
    float4* bxg = (float4*)((char*)d_ws + off);                  // 512 KB
    off += (size_t)BATCH * SORT2 * 16;
    off = (off + 255) & ~(size_t)255;
    u64* mask = (u64*)((char*)d_ws + off);                       // 8 MB
    off += (size_t)BATCH * SORT2 * NWORD * 8;
    off = (off + 255) & ~(size_t)255;
    float4* fbbox = (float4*)((char*)d_ws + off);                // 1.5 MB (fallback)

    compact_kernel   <<<BATCH * BPB, 256, 0, stream>>>(scores, cnt_blk, cand);
    sort_kernel      <<<BATCH, 512, 0, stream>>>(cnt_blk, cand, deltas, im_info,
                                                 bxg, m2arr, okarr);
    mask_kernel      <<<BATCH * 32, 256, 0, stream>>>(bxg, m2arr, okarr, mask);
    resolve_fb_kernel<<<BATCH, 512, 0, stream>>>(bxg, mask, m2arr, okarr,
                                                 scores, deltas, im_info,
                                                 fbbox, out);
}